// Round 1
// baseline (326.782 us; speedup 1.0000x reference)
//
#include <hip/hip_runtime.h>

// ---------------------------------------------------------------------------
// MaximumMeanDiscrepancy: BATCH=160, INSTANCES=4, FEAT=1024, P=40
// out[0] = mmd(wcs, wct), out[1] = mmd(bcs, bct)
// ---------------------------------------------------------------------------

#define FEAT   1024
#define NROW   160     // BATCH
#define PGRP   40      // P
#define NPAIR  1522    // 1 + 39*39
#define NBC    6088    // NPAIR*4
#define NWC    160

// workspace layout (float offsets)
#define WS_ES   0          // E_s [160*160]
#define WS_ET   25600      // E_t [160*160]
#define WS_BCS  51200      // bc_s [6088*4]
#define WS_BCT  75552      // bc_t [6088*4]
#define WS_WCS  99904      // wc_s [160*4]
#define WS_WCT  100544     // wc_t [160*4]
#define WS_ACC_BYTES 404736  // 6 doubles, 8B aligned

struct Coef { float c[19]; };

// --- kernel 1: E[a,b] = ||f_a - f_b||^2 for both sides, 16x16 tiles ---------
__global__ __launch_bounds__(256) void compute_E(const float* __restrict__ Fs,
                                                 const float* __restrict__ Ft,
                                                 float* __restrict__ ws) {
    int side = blockIdx.x / 100;          // 0 = source, 1 = target
    int tile = blockIdx.x % 100;
    int trow = tile / 10, tcol = tile % 10;
    const float* F = side ? Ft : Fs;
    float* E = ws + (side ? WS_ET : WS_ES);

    __shared__ float As[16][132];
    __shared__ float Bs[16][132];
    int tid = threadIdx.x;
    int ti = tid >> 4, tj = tid & 15;
    int lr = tid >> 5;        // 0..7
    int lc4 = tid & 31;       // float4 column (0..31) of 128-dim chunk

    float acc = 0.f;
    for (int ch = 0; ch < 8; ++ch) {
        for (int rr = lr; rr < 16; rr += 8) {
            float4 a = *(const float4*)(F + (trow*16+rr)*FEAT + ch*128 + lc4*4);
            *(float4*)(&As[rr][lc4*4]) = a;
            float4 b = *(const float4*)(F + (tcol*16+rr)*FEAT + ch*128 + lc4*4);
            *(float4*)(&Bs[rr][lc4*4]) = b;
        }
        __syncthreads();
        #pragma unroll
        for (int c = 0; c < 128; c += 4) {
            float4 a = *(const float4*)(&As[ti][c]);
            float4 b = *(const float4*)(&Bs[tj][c]);
            float d0 = a.x - b.x, d1 = a.y - b.y, d2 = a.z - b.z, d3 = a.w - b.w;
            acc = fmaf(d0, d0, acc);
            acc = fmaf(d1, d1, acc);
            acc = fmaf(d2, d2, acc);
            acc = fmaf(d3, d3, acc);
        }
        __syncthreads();
    }
    E[(trow*16+ti)*NROW + tcol*16 + tj] = acc;
}

// --- kernel 2: gather wc/bc rows from E; zero the 6 accumulators ------------
__global__ __launch_bounds__(256) void scatter(float* __restrict__ ws) {
    int idx = blockIdx.x * blockDim.x + threadIdx.x;
    const float* E_s = ws + WS_ES;
    const float* E_t = ws + WS_ET;
    float4* bc_s = (float4*)(ws + WS_BCS);
    float4* bc_t = (float4*)(ws + WS_BCT);
    float4* wc_s = (float4*)(ws + WS_WCS);
    float4* wc_t = (float4*)(ws + WS_WCT);
    double* accs = (double*)((char*)ws + WS_ACC_BYTES);

    if (idx < 6) accs[idx] = 0.0;

    if (idx < NBC) {
        int t = idx >> 2, ii = idx & 3;
        int pi, pj;
        if (t == 0) { pi = 0; pj = 1; }
        else {
            int tt = t - 1;
            pi = 1 + tt / 39;
            int jj = tt % 39;
            pj = (jj < pi) ? jj : jj + 1;
        }
        bc_s[idx] = *(const float4*)(E_s + (4*pi + ii)*NROW + 4*pj);
        bc_t[idx] = *(const float4*)(E_t + (4*pi + ii)*NROW + 4*pj);
    } else if (idx < NBC + NWC) {
        int r = idx - NBC;
        int p = r >> 2;
        wc_s[r] = *(const float4*)(E_s + r*NROW + 4*p);
        wc_t[r] = *(const float4*)(E_t + r*NROW + 4*p);
    }
}

// --- kernel 3: the 6 multi-bandwidth Gaussian-kernel sums -------------------
// grid = (NBC, 6); job y: 0 wc_ss, 1 wc_tt, 2 wc_st, 3 bc_ss, 4 bc_tt, 5 bc_st
__global__ __launch_bounds__(256) void gk_all(const float* __restrict__ ws, Coef co) {
    const float4* wcs = (const float4*)(ws + WS_WCS);
    const float4* wct = (const float4*)(ws + WS_WCT);
    const float4* bcs = (const float4*)(ws + WS_BCS);
    const float4* bct = (const float4*)(ws + WS_BCT);
    double* accs = (double*)((const char*)ws + WS_ACC_BYTES);

    int job = blockIdx.y;
    const float4 *X, *Y;
    int N;
    switch (job) {
        case 0: X = wcs; Y = wcs; N = NWC; break;
        case 1: X = wct; Y = wct; N = NWC; break;
        case 2: X = wcs; Y = wct; N = NWC; break;
        case 3: X = bcs; Y = bcs; N = NBC; break;
        case 4: X = bct; Y = bct; N = NBC; break;
        default: X = bcs; Y = bct; N = NBC; break;
    }

    int i = blockIdx.x;
    if (i >= N) return;
    float4 x = X[i];

    double acc = 0.0;
    for (int j = threadIdx.x; j < N; j += 256) {
        float4 y = Y[j];
        float d0 = x.x - y.x, d1 = x.y - y.y, d2 = x.z - y.z, d3 = x.w - y.w;
        float d = d0 * d0;
        d = fmaf(d1, d1, d);
        d = fmaf(d2, d2, d);
        d = fmaf(d3, d3, d);
        float s = 0.f;
        #pragma unroll
        for (int k = 0; k < 19; ++k) s += __expf(d * co.c[k]);
        acc += (double)s;
    }

    // wave reduce (64 lanes), then block reduce 4 waves
    #pragma unroll
    for (int off = 32; off; off >>= 1) acc += __shfl_down(acc, off, 64);
    __shared__ double wsum[4];
    int lane = threadIdx.x & 63, w = threadIdx.x >> 6;
    if (lane == 0) wsum[w] = acc;
    __syncthreads();
    if (threadIdx.x == 0) {
        double tot = wsum[0] + wsum[1] + wsum[2] + wsum[3];
        atomicAdd(&accs[job], tot);
    }
}

// --- kernel 4: combine into the two output scalars --------------------------
__global__ void finalize(const float* __restrict__ ws, float* __restrict__ out) {
    if (threadIdx.x == 0) {
        const double* accs = (const double*)((const char*)ws + WS_ACC_BYTES);
        double nw = (double)NWC * (double)NWC;
        double nb = (double)NBC * (double)NBC;
        out[0] = (float)((accs[0] + accs[1] - 2.0 * accs[2]) / nw);
        out[1] = (float)((accs[3] + accs[4] - 2.0 * accs[5]) / nb);
    }
}

extern "C" void kernel_launch(void* const* d_in, const int* in_sizes, int n_in,
                              void* d_out, int out_size, void* d_ws, size_t ws_size,
                              hipStream_t stream) {
    const float* src = (const float*)d_in[0];
    const float* tgt = (const float*)d_in[1];
    float* out = (float*)d_out;
    float* ws = (float*)d_ws;

    static const float SIG[19] = {1e-06f, 1e-05f, 1e-04f, 1e-03f, 1e-02f, 1e-01f,
                                  1.0f, 5.0f, 10.0f, 15.0f, 20.0f, 25.0f, 30.0f,
                                  35.0f, 100.0f, 1e3f, 1e4f, 1e5f, 1e6f};
    Coef co;
    for (int k = 0; k < 19; ++k) co.c[k] = (float)(-1.0 / (2.0 * (double)SIG[k]));

    compute_E<<<200, 256, 0, stream>>>(src, tgt, ws);
    scatter<<<26, 256, 0, stream>>>(ws);
    dim3 g(NBC, 6);
    gk_all<<<g, 256, 0, stream>>>(ws, co);
    finalize<<<1, 64, 0, stream>>>(ws, out);
}

// Round 2
// 113.898 us; speedup vs baseline: 2.8691x; 2.8691x over previous
//
#include <hip/hip_runtime.h>

// ---------------------------------------------------------------------------
// MaximumMeanDiscrepancy: BATCH=160, INSTANCES=4, FEAT=1024, P=40
// out[0] = mmd(wcs, wct), out[1] = mmd(bcs, bct)
// ---------------------------------------------------------------------------

#define FEAT   1024
#define NROW   160     // BATCH
#define NPAIR  1522    // 1 + 39*39
#define NBC    6088    // NPAIR*4
#define NWC    160

// workspace layout (float offsets)
#define WS_ES   0          // E_s [160*160]
#define WS_ET   25600      // E_t [160*160]
#define WS_BCS  51200      // bc_s [6088*4]
#define WS_BCT  75552      // bc_t [6088*4]
#define WS_WCS  99904      // wc_s [160*4]
#define WS_WCT  100544     // wc_t [160*4]
#define WS_ACC_BYTES 404736  // 6*64 doubles
#define NSLOT  64

struct Coef { float c[19]; };  // c[k] = -log2(e)/(2*sigma_k)  (exp2 form)

#if defined(__has_builtin)
#if __has_builtin(__builtin_amdgcn_exp2f)
#define EXP2(x) __builtin_amdgcn_exp2f(x)
#else
#define EXP2(x) exp2f(x)
#endif
#else
#define EXP2(x) exp2f(x)
#endif

// --- kernel 1: E[a,b] = ||f_a - f_b||^2 for both sides, 16x16 tiles ---------
__global__ __launch_bounds__(256) void compute_E(const float* __restrict__ Fs,
                                                 const float* __restrict__ Ft,
                                                 float* __restrict__ ws) {
    int side = blockIdx.x / 100;          // 0 = source, 1 = target
    int tile = blockIdx.x % 100;
    int trow = tile / 10, tcol = tile % 10;
    const float* F = side ? Ft : Fs;
    float* E = ws + (side ? WS_ET : WS_ES);

    __shared__ float As[16][132];
    __shared__ float Bs[16][132];
    int tid = threadIdx.x;
    int ti = tid >> 4, tj = tid & 15;
    int lr = tid >> 5;        // 0..7
    int lc4 = tid & 31;       // float4 column (0..31) of 128-dim chunk

    float acc = 0.f;
    for (int ch = 0; ch < 8; ++ch) {
        for (int rr = lr; rr < 16; rr += 8) {
            float4 a = *(const float4*)(F + (trow*16+rr)*FEAT + ch*128 + lc4*4);
            *(float4*)(&As[rr][lc4*4]) = a;
            float4 b = *(const float4*)(F + (tcol*16+rr)*FEAT + ch*128 + lc4*4);
            *(float4*)(&Bs[rr][lc4*4]) = b;
        }
        __syncthreads();
        #pragma unroll
        for (int c = 0; c < 128; c += 4) {
            float4 a = *(const float4*)(&As[ti][c]);
            float4 b = *(const float4*)(&Bs[tj][c]);
            float d0 = a.x - b.x, d1 = a.y - b.y, d2 = a.z - b.z, d3 = a.w - b.w;
            acc = fmaf(d0, d0, acc);
            acc = fmaf(d1, d1, acc);
            acc = fmaf(d2, d2, acc);
            acc = fmaf(d3, d3, acc);
        }
        __syncthreads();
    }
    E[(trow*16+ti)*NROW + tcol*16 + tj] = acc;
}

// --- kernel 2: gather wc/bc rows from E; zero the accumulators --------------
__global__ __launch_bounds__(256) void scatter(float* __restrict__ ws) {
    int idx = blockIdx.x * blockDim.x + threadIdx.x;
    const float* E_s = ws + WS_ES;
    const float* E_t = ws + WS_ET;
    float4* bc_s = (float4*)(ws + WS_BCS);
    float4* bc_t = (float4*)(ws + WS_BCT);
    float4* wc_s = (float4*)(ws + WS_WCS);
    float4* wc_t = (float4*)(ws + WS_WCT);
    double* accs = (double*)((char*)ws + WS_ACC_BYTES);

    if (idx < 6 * NSLOT) accs[idx] = 0.0;

    if (idx < NBC) {
        int t = idx >> 2, ii = idx & 3;
        int pi, pj;
        if (t == 0) { pi = 0; pj = 1; }
        else {
            int tt = t - 1;
            pi = 1 + tt / 39;
            int jj = tt % 39;
            pj = (jj < pi) ? jj : jj + 1;
        }
        bc_s[idx] = *(const float4*)(E_s + (4*pi + ii)*NROW + 4*pj);
        bc_t[idx] = *(const float4*)(E_t + (4*pi + ii)*NROW + 4*pj);
    } else if (idx < NBC + NWC) {
        int r = idx - NBC;
        int p = r >> 2;
        wc_s[r] = *(const float4*)(E_s + r*NROW + 4*p);
        wc_t[r] = *(const float4*)(E_t + r*NROW + 4*p);
    }
}

// --- pair evaluation: tiered multi-bandwidth Gaussian kernel sum ------------
// Skip tiers only when every term in the tier underflows to EXACT fp32 zero:
// exp2(d*c) == 0 when d*c <= -150  ->  d >= 210*sigma_max_in_tier (conservative;
// true bound is ~208*sigma). Adding an exact 0.0f never changes the fp32 sum.
__device__ __forceinline__ double row_accum(const float4* __restrict__ Y, float4 x,
                                            int jbeg, int N, const Coef& co) {
    double acc = 0.0;
    for (int j = jbeg + (int)threadIdx.x; j < N; j += 256) {
        float4 y = Y[j];
        float d0 = x.x - y.x, d1 = x.y - y.y, d2 = x.z - y.z, d3 = x.w - y.w;
        float d = d0 * d0;
        d = fmaf(d1, d1, d);
        d = fmaf(d2, d2, d);
        d = fmaf(d3, d3, d);
        // always: sigma = 100, 1e3, 1e4, 1e5, 1e6
        float s = EXP2(d * co.c[14]) + EXP2(d * co.c[15]) + EXP2(d * co.c[16])
                + EXP2(d * co.c[17]) + EXP2(d * co.c[18]);
        if (d < 7350.0f)   // sigma = 20, 25, 30, 35  (210*35)
            s += EXP2(d * co.c[10]) + EXP2(d * co.c[11])
               + EXP2(d * co.c[12]) + EXP2(d * co.c[13]);
        if (d < 3150.0f)   // sigma = 5, 10, 15  (210*15)
            s += EXP2(d * co.c[7]) + EXP2(d * co.c[8]) + EXP2(d * co.c[9]);
        if (d < 210.0f)    // sigma <= 1  (210*1)
            s += EXP2(d * co.c[0]) + EXP2(d * co.c[1]) + EXP2(d * co.c[2])
               + EXP2(d * co.c[3]) + EXP2(d * co.c[4]) + EXP2(d * co.c[5])
               + EXP2(d * co.c[6]);
        acc += (double)s;
    }
    return acc;
}

// --- kernel 3: the 6 multi-bandwidth Gaussian-kernel sums -------------------
// jobs: 0 wc_ss, 1 wc_tt, 2 wc_st, 3 bc_ss, 4 bc_tt, 5 bc_st
// self jobs (0,1,3,4) are bit-exact symmetric in difference-form distance:
// compute strict upper triangle only (x2 and +19*N diag handled in finalize).
// Row balance: block b handles rows b and N-1-b (lengths sum to N-1).
__global__ __launch_bounds__(256) void gk_all(float* __restrict__ ws, Coef co) {
    const float4* wcs = (const float4*)(ws + WS_WCS);
    const float4* wct = (const float4*)(ws + WS_WCT);
    const float4* bcs = (const float4*)(ws + WS_BCS);
    const float4* bct = (const float4*)(ws + WS_BCT);
    double* accs = (double*)((char*)ws + WS_ACC_BYTES);

    int job = blockIdx.y;
    const float4 *X, *Y;
    int N; bool sym;
    switch (job) {
        case 0:  X = wcs; Y = wcs; N = NWC; sym = true;  break;
        case 1:  X = wct; Y = wct; N = NWC; sym = true;  break;
        case 2:  X = wcs; Y = wct; N = NWC; sym = false; break;
        case 3:  X = bcs; Y = bcs; N = NBC; sym = true;  break;
        case 4:  X = bct; Y = bct; N = NBC; sym = true;  break;
        default: X = bcs; Y = bct; N = NBC; sym = false; break;
    }

    int i = blockIdx.x;
    int lim = sym ? (N >> 1) : N;
    if (i >= lim) return;

    double acc = 0.0;
    if (sym) {
        float4 x0 = X[i];
        acc += row_accum(Y, x0, i + 1, N, co);
        int i1 = N - 1 - i;
        float4 x1 = X[i1];
        acc += row_accum(Y, x1, i1 + 1, N, co);
    } else {
        float4 x = X[i];
        acc += row_accum(Y, x, 0, N, co);
    }

    // wave reduce (64 lanes), then block reduce 4 waves
    #pragma unroll
    for (int off = 32; off; off >>= 1) acc += __shfl_down(acc, off, 64);
    __shared__ double wsum[4];
    int lane = threadIdx.x & 63, w = threadIdx.x >> 6;
    if (lane == 0) wsum[w] = acc;
    __syncthreads();
    if (threadIdx.x == 0) {
        double tot = wsum[0] + wsum[1] + wsum[2] + wsum[3];
        atomicAdd(&accs[job * NSLOT + (blockIdx.x & (NSLOT - 1))], tot);
    }
}

// --- kernel 4: combine into the two output scalars --------------------------
__global__ void finalize(const float* __restrict__ ws, float* __restrict__ out) {
    const double* accs = (const double*)((const char*)ws + WS_ACC_BYTES);
    int lane = threadIdx.x;  // blockDim = 64
    double p[6];
    #pragma unroll
    for (int q = 0; q < 6; ++q) {
        p[q] = accs[q * NSLOT + lane];
        #pragma unroll
        for (int off = 32; off; off >>= 1) p[q] += __shfl_down(p[q], off, 64);
    }
    if (lane == 0) {
        double t0 = 2.0 * p[0] + 19.0 * NWC;   // self: 2*triangle + diag(19 each)
        double t1 = 2.0 * p[1] + 19.0 * NWC;
        double t3 = 2.0 * p[3] + 19.0 * NBC;
        double t4 = 2.0 * p[4] + 19.0 * NBC;
        double nw = (double)NWC * (double)NWC;
        double nb = (double)NBC * (double)NBC;
        out[0] = (float)((t0 + t1 - 2.0 * p[2]) / nw);
        out[1] = (float)((t3 + t4 - 2.0 * p[5]) / nb);
    }
}

extern "C" void kernel_launch(void* const* d_in, const int* in_sizes, int n_in,
                              void* d_out, int out_size, void* d_ws, size_t ws_size,
                              hipStream_t stream) {
    const float* src = (const float*)d_in[0];
    const float* tgt = (const float*)d_in[1];
    float* out = (float*)d_out;
    float* ws = (float*)d_ws;

    static const double SIG[19] = {1e-06, 1e-05, 1e-04, 1e-03, 1e-02, 1e-01,
                                   1.0, 5.0, 10.0, 15.0, 20.0, 25.0, 30.0,
                                   35.0, 100.0, 1e3, 1e4, 1e5, 1e6};
    Coef co;
    for (int k = 0; k < 19; ++k)
        co.c[k] = (float)(-1.0 / (2.0 * SIG[k] * 0.6931471805599453));  // -log2e/(2s)

    compute_E<<<200, 256, 0, stream>>>(src, tgt, ws);
    scatter<<<26, 256, 0, stream>>>(ws);
    dim3 g(NBC, 6);
    gk_all<<<g, 256, 0, stream>>>(ws, co);
    finalize<<<1, 64, 0, stream>>>(ws, out);
}

// Round 3
// 110.828 us; speedup vs baseline: 2.9486x; 1.0277x over previous
//
#include <hip/hip_runtime.h>

// ---------------------------------------------------------------------------
// MaximumMeanDiscrepancy: BATCH=160, INSTANCES=4, FEAT=1024, P=40
// out[0] = mmd(wcs, wct), out[1] = mmd(bcs, bct)
// ---------------------------------------------------------------------------

#define FEAT   1024
#define NROW   160     // BATCH
#define NPAIR  1522    // 1 + 39*39
#define NBC    6088    // NPAIR*4
#define NWC    160

// workspace layout (float offsets)
#define WS_ES   0          // E_s [160*160]
#define WS_ET   25600      // E_t [160*160]
#define WS_BCS  51200      // bc_s [6088*4]
#define WS_BCT  75552      // bc_t [6088*4]
#define WS_WCS  99904      // wc_s [160*4]
#define WS_WCT  100544     // wc_t [160*4]
#define WS_ACC_BYTES 404736  // 6*64 doubles
#define NSLOT  64

// flattened gk grid ranges: job lims {80,80,160,3044,3044,6088}
#define GK_B0   80
#define GK_B1   160
#define GK_B2   320
#define GK_B3   3364
#define GK_B4   6408
#define GK_B5   12496

struct Coef { float c[19]; };  // c[k] = -log2(e)/(2*sigma_k)  (exp2 form)

#if defined(__has_builtin)
#if __has_builtin(__builtin_amdgcn_exp2f)
#define EXP2(x) __builtin_amdgcn_exp2f(x)
#else
#define EXP2(x) exp2f(x)
#endif
#else
#define EXP2(x) exp2f(x)
#endif

// --- kernel 1: E[a,b] = ||f_a - f_b||^2 for both sides, 16x16 tiles ---------
__global__ __launch_bounds__(256) void compute_E(const float* __restrict__ Fs,
                                                 const float* __restrict__ Ft,
                                                 float* __restrict__ ws) {
    int side = blockIdx.x / 100;          // 0 = source, 1 = target
    int tile = blockIdx.x % 100;
    int trow = tile / 10, tcol = tile % 10;
    const float* F = side ? Ft : Fs;
    float* E = ws + (side ? WS_ET : WS_ES);

    __shared__ float As[16][132];
    __shared__ float Bs[16][132];
    int tid = threadIdx.x;
    int ti = tid >> 4, tj = tid & 15;
    int lr = tid >> 5;        // 0..7
    int lc4 = tid & 31;       // float4 column (0..31) of 128-dim chunk

    float acc = 0.f;
    for (int ch = 0; ch < 8; ++ch) {
        for (int rr = lr; rr < 16; rr += 8) {
            float4 a = *(const float4*)(F + (trow*16+rr)*FEAT + ch*128 + lc4*4);
            *(float4*)(&As[rr][lc4*4]) = a;
            float4 b = *(const float4*)(F + (tcol*16+rr)*FEAT + ch*128 + lc4*4);
            *(float4*)(&Bs[rr][lc4*4]) = b;
        }
        __syncthreads();
        #pragma unroll
        for (int c = 0; c < 128; c += 4) {
            float4 a = *(const float4*)(&As[ti][c]);
            float4 b = *(const float4*)(&Bs[tj][c]);
            float d0 = a.x - b.x, d1 = a.y - b.y, d2 = a.z - b.z, d3 = a.w - b.w;
            acc = fmaf(d0, d0, acc);
            acc = fmaf(d1, d1, acc);
            acc = fmaf(d2, d2, acc);
            acc = fmaf(d3, d3, acc);
        }
        __syncthreads();
    }
    E[(trow*16+ti)*NROW + tcol*16 + tj] = acc;
}

// --- kernel 2: gather wc/bc rows from E; zero the accumulators --------------
__global__ __launch_bounds__(256) void scatter(float* __restrict__ ws) {
    int idx = blockIdx.x * blockDim.x + threadIdx.x;
    const float* E_s = ws + WS_ES;
    const float* E_t = ws + WS_ET;
    float4* bc_s = (float4*)(ws + WS_BCS);
    float4* bc_t = (float4*)(ws + WS_BCT);
    float4* wc_s = (float4*)(ws + WS_WCS);
    float4* wc_t = (float4*)(ws + WS_WCT);
    double* accs = (double*)((char*)ws + WS_ACC_BYTES);

    if (idx < 6 * NSLOT) accs[idx] = 0.0;

    if (idx < NBC) {
        int t = idx >> 2, ii = idx & 3;
        int pi, pj;
        if (t == 0) { pi = 0; pj = 1; }
        else {
            int tt = t - 1;
            pi = 1 + tt / 39;
            int jj = tt % 39;
            pj = (jj < pi) ? jj : jj + 1;
        }
        bc_s[idx] = *(const float4*)(E_s + (4*pi + ii)*NROW + 4*pj);
        bc_t[idx] = *(const float4*)(E_t + (4*pi + ii)*NROW + 4*pj);
    } else if (idx < NBC + NWC) {
        int r = idx - NBC;
        int p = r >> 2;
        wc_s[r] = *(const float4*)(E_s + r*NROW + 4*p);
        wc_t[r] = *(const float4*)(E_t + r*NROW + 4*p);
    }
}

// --- tiered multi-bandwidth Gaussian kernel sum -----------------------------
// exp2(d*c) is EXACTLY 0.0f once d*c <= -150 (below smallest denormal), so a
// tier may be skipped iff d >= 150*2*sigma*ln2 for every sigma in it:
//   sigma=100 -> 20794.4; sigma<=35 -> 7278; sigma<=15 -> 3119; sigma<=1 -> 208.
// All conditional tiers sit under ONE branch so the compiler emits a real
// exec-mask branch (mostly skipped) instead of if-converting 8 extra exps.
__device__ __forceinline__ float pair_sum(float d, const Coef& co) {
    float s = EXP2(d * co.c[15]) + EXP2(d * co.c[16])     // 1e3, 1e4
            + EXP2(d * co.c[17]) + EXP2(d * co.c[18]);    // 1e5, 1e6
    if (d < 20795.0f) {
        s += EXP2(d * co.c[14]);                          // 100
        if (d < 7280.0f)
            s += EXP2(d * co.c[10]) + EXP2(d * co.c[11])
               + EXP2(d * co.c[12]) + EXP2(d * co.c[13]); // 20,25,30,35
        if (d < 3120.0f)
            s += EXP2(d * co.c[7]) + EXP2(d * co.c[8]) + EXP2(d * co.c[9]);
        if (d < 208.0f)
            s += EXP2(d * co.c[0]) + EXP2(d * co.c[1]) + EXP2(d * co.c[2])
               + EXP2(d * co.c[3]) + EXP2(d * co.c[4]) + EXP2(d * co.c[5])
               + EXP2(d * co.c[6]);
    }
    return s;
}

__device__ __forceinline__ double row_accum(const float4* __restrict__ Y, float4 x,
                                            int jbeg, int N, const Coef& co) {
    double acc = 0.0;
    for (int j = jbeg + (int)threadIdx.x; j < N; j += 256) {
        float4 y = Y[j];
        float d0 = x.x - y.x, d1 = x.y - y.y, d2 = x.z - y.z, d3 = x.w - y.w;
        float d = d0 * d0;
        d = fmaf(d1, d1, d);
        d = fmaf(d2, d2, d);
        d = fmaf(d3, d3, d);
        acc += (double)pair_sum(d, co);
    }
    return acc;
}

// --- kernel 3: the 6 multi-bandwidth Gaussian-kernel sums -------------------
// jobs: 0 wc_ss, 1 wc_tt, 2 wc_st, 3 bc_ss, 4 bc_tt, 5 bc_st
// self jobs (0,1,3,4) are bit-exact symmetric in difference-form distance:
// strict upper triangle only (x2 and +19*N diag handled in finalize).
// Row balance: block b handles rows b and N-1-b (lengths sum to N-1).
// Grid is flattened to only useful blocks (range decode below).
__global__ __launch_bounds__(256) void gk_all(float* __restrict__ ws, Coef co) {
    const float4* wcs = (const float4*)(ws + WS_WCS);
    const float4* wct = (const float4*)(ws + WS_WCT);
    const float4* bcs = (const float4*)(ws + WS_BCS);
    const float4* bct = (const float4*)(ws + WS_BCT);
    double* accs = (double*)((char*)ws + WS_ACC_BYTES);

    int b = blockIdx.x;
    int job, i;
    const float4 *X, *Y;
    int N; bool sym;
    if (b < GK_B2) {
        N = NWC;
        if (b < GK_B0)      { job = 0; i = b;          X = wcs; Y = wcs; sym = true;  }
        else if (b < GK_B1) { job = 1; i = b - GK_B0;  X = wct; Y = wct; sym = true;  }
        else                { job = 2; i = b - GK_B1;  X = wcs; Y = wct; sym = false; }
    } else {
        N = NBC;
        if (b < GK_B3)      { job = 3; i = b - GK_B2;  X = bcs; Y = bcs; sym = true;  }
        else if (b < GK_B4) { job = 4; i = b - GK_B3;  X = bct; Y = bct; sym = true;  }
        else                { job = 5; i = b - GK_B4;  X = bcs; Y = bct; sym = false; }
    }

    double acc = 0.0;
    if (sym) {
        float4 x0 = X[i];
        acc += row_accum(Y, x0, i + 1, N, co);
        int i1 = N - 1 - i;
        float4 x1 = X[i1];
        acc += row_accum(Y, x1, i1 + 1, N, co);
    } else {
        float4 x = X[i];
        acc += row_accum(Y, x, 0, N, co);
    }

    // wave reduce (64 lanes), then block reduce 4 waves
    #pragma unroll
    for (int off = 32; off; off >>= 1) acc += __shfl_down(acc, off, 64);
    __shared__ double wsum[4];
    int lane = threadIdx.x & 63, w = threadIdx.x >> 6;
    if (lane == 0) wsum[w] = acc;
    __syncthreads();
    if (threadIdx.x == 0) {
        double tot = wsum[0] + wsum[1] + wsum[2] + wsum[3];
        atomicAdd(&accs[job * NSLOT + (blockIdx.x & (NSLOT - 1))], tot);
    }
}

// --- kernel 4: combine into the two output scalars --------------------------
__global__ void finalize(const float* __restrict__ ws, float* __restrict__ out) {
    const double* accs = (const double*)((const char*)ws + WS_ACC_BYTES);
    int lane = threadIdx.x;  // blockDim = 64
    double p[6];
    #pragma unroll
    for (int q = 0; q < 6; ++q) {
        p[q] = accs[q * NSLOT + lane];
        #pragma unroll
        for (int off = 32; off; off >>= 1) p[q] += __shfl_down(p[q], off, 64);
    }
    if (lane == 0) {
        double t0 = 2.0 * p[0] + 19.0 * NWC;   // self: 2*triangle + diag(19 each)
        double t1 = 2.0 * p[1] + 19.0 * NWC;
        double t3 = 2.0 * p[3] + 19.0 * NBC;
        double t4 = 2.0 * p[4] + 19.0 * NBC;
        double nw = (double)NWC * (double)NWC;
        double nb = (double)NBC * (double)NBC;
        out[0] = (float)((t0 + t1 - 2.0 * p[2]) / nw);
        out[1] = (float)((t3 + t4 - 2.0 * p[5]) / nb);
    }
}

extern "C" void kernel_launch(void* const* d_in, const int* in_sizes, int n_in,
                              void* d_out, int out_size, void* d_ws, size_t ws_size,
                              hipStream_t stream) {
    const float* src = (const float*)d_in[0];
    const float* tgt = (const float*)d_in[1];
    float* out = (float*)d_out;
    float* ws = (float*)d_ws;

    static const double SIG[19] = {1e-06, 1e-05, 1e-04, 1e-03, 1e-02, 1e-01,
                                   1.0, 5.0, 10.0, 15.0, 20.0, 25.0, 30.0,
                                   35.0, 100.0, 1e3, 1e4, 1e5, 1e6};
    Coef co;
    for (int k = 0; k < 19; ++k)
        co.c[k] = (float)(-1.0 / (2.0 * SIG[k] * 0.6931471805599453));  // -log2e/(2s)

    compute_E<<<200, 256, 0, stream>>>(src, tgt, ws);
    scatter<<<26, 256, 0, stream>>>(ws);
    gk_all<<<GK_B5, 256, 0, stream>>>(ws, co);
    finalize<<<1, 64, 0, stream>>>(ws, out);
}

// Round 4
// 90.461 us; speedup vs baseline: 3.6124x; 1.2252x over previous
//
#include <hip/hip_runtime.h>

// ---------------------------------------------------------------------------
// MaximumMeanDiscrepancy: BATCH=160, INSTANCES=4, FEAT=1024, P=40
// out[0] = mmd(wcs, wct), out[1] = mmd(bcs, bct)
// ---------------------------------------------------------------------------

#define FEAT   1024
#define NROW   160     // BATCH
#define NPAIR  1522    // 1 + 39*39
#define NBC    6088    // NPAIR*4
#define NWC    160

// workspace layout (float offsets). bc/wc arrays are padded with 256 rows of
// 1e19f so the j-loop can run a uniform trip count: padded rows give d = inf
// -> every exp2 term is an exact 0.0f and the pair is never "hot".
#define WS_ES   0          // E_s [160*160]
#define WS_ET   25600      // E_t [160*160]
#define WS_BCS  51200      // bc_s [(6088+256)*4]
#define WS_BCT  76576      // bc_t
#define WS_WCS  101952     // wc_s [(160+256)*4]
#define WS_WCT  103616     // wc_t
#define WS_ACC_BYTES 421120  // 6*64 doubles
#define NSLOT  64

// flattened gk grid ranges: job lims {80,80,160,3044,3044,6088}
#define GK_B0   80
#define GK_B1   160
#define GK_B2   320
#define GK_B3   3364
#define GK_B4   6408
#define GK_B5   12496

struct Coef { float c[19]; };  // c[k] = -log2(e)/(2*sigma_k)  (exp2 form)

#if defined(__has_builtin)
#if __has_builtin(__builtin_amdgcn_exp2f)
#define EXP2(x) __builtin_amdgcn_exp2f(x)
#else
#define EXP2(x) exp2f(x)
#endif
#else
#define EXP2(x) exp2f(x)
#endif

// --- kernel 1: E[a,b] = ||f_a - f_b||^2 for both sides, 16x16 tiles ---------
__global__ __launch_bounds__(256) void compute_E(const float* __restrict__ Fs,
                                                 const float* __restrict__ Ft,
                                                 float* __restrict__ ws) {
    int side = blockIdx.x / 100;          // 0 = source, 1 = target
    int tile = blockIdx.x % 100;
    int trow = tile / 10, tcol = tile % 10;
    const float* F = side ? Ft : Fs;
    float* E = ws + (side ? WS_ET : WS_ES);

    __shared__ float As[16][132];
    __shared__ float Bs[16][132];
    int tid = threadIdx.x;
    int ti = tid >> 4, tj = tid & 15;
    int lr = tid >> 5;        // 0..7
    int lc4 = tid & 31;       // float4 column (0..31) of 128-dim chunk

    float acc = 0.f;
    for (int ch = 0; ch < 8; ++ch) {
        for (int rr = lr; rr < 16; rr += 8) {
            float4 a = *(const float4*)(F + (trow*16+rr)*FEAT + ch*128 + lc4*4);
            *(float4*)(&As[rr][lc4*4]) = a;
            float4 b = *(const float4*)(F + (tcol*16+rr)*FEAT + ch*128 + lc4*4);
            *(float4*)(&Bs[rr][lc4*4]) = b;
        }
        __syncthreads();
        #pragma unroll
        for (int c = 0; c < 128; c += 4) {
            float4 a = *(const float4*)(&As[ti][c]);
            float4 b = *(const float4*)(&Bs[tj][c]);
            float d0 = a.x - b.x, d1 = a.y - b.y, d2 = a.z - b.z, d3 = a.w - b.w;
            acc = fmaf(d0, d0, acc);
            acc = fmaf(d1, d1, acc);
            acc = fmaf(d2, d2, acc);
            acc = fmaf(d3, d3, acc);
        }
        __syncthreads();
    }
    E[(trow*16+ti)*NROW + tcol*16 + tj] = acc;
}

// --- kernel 2: gather wc/bc rows from E; pad rows; zero accumulators --------
__global__ __launch_bounds__(256) void scatter(float* __restrict__ ws) {
    int idx = blockIdx.x * blockDim.x + threadIdx.x;
    const float* E_s = ws + WS_ES;
    const float* E_t = ws + WS_ET;
    float4* bc_s = (float4*)(ws + WS_BCS);
    float4* bc_t = (float4*)(ws + WS_BCT);
    float4* wc_s = (float4*)(ws + WS_WCS);
    float4* wc_t = (float4*)(ws + WS_WCT);
    double* accs = (double*)((char*)ws + WS_ACC_BYTES);

    if (idx < 6 * NSLOT) accs[idx] = 0.0;

    if (idx < NBC) {
        int t = idx >> 2, ii = idx & 3;
        int pi, pj;
        if (t == 0) { pi = 0; pj = 1; }
        else {
            int tt = t - 1;
            pi = 1 + tt / 39;
            int jj = tt % 39;
            pj = (jj < pi) ? jj : jj + 1;
        }
        bc_s[idx] = *(const float4*)(E_s + (4*pi + ii)*NROW + 4*pj);
        bc_t[idx] = *(const float4*)(E_t + (4*pi + ii)*NROW + 4*pj);
    } else if (idx < NBC + NWC) {
        int r = idx - NBC;
        int p = r >> 2;
        wc_s[r] = *(const float4*)(E_s + r*NROW + 4*p);
        wc_t[r] = *(const float4*)(E_t + r*NROW + 4*p);
    } else if (idx < NBC + NWC + 256) {
        int p = idx - (NBC + NWC);
        float4 pad = make_float4(1e19f, 1e19f, 1e19f, 1e19f);
        bc_s[NBC + p] = pad;
        bc_t[NBC + p] = pad;
    } else if (idx < NBC + NWC + 512) {
        int p = idx - (NBC + NWC + 256);
        float4 pad = make_float4(1e19f, 1e19f, 1e19f, 1e19f);
        wc_s[NWC + p] = pad;
        wc_t[NWC + p] = pad;
    }
}

// --- tail terms for hot pairs (d < 7280): sigma <= 35 tiers -----------------
// Tier-skip is exact: exp2(d*c) == 0.0f once d*c <= -150 (below half the
// smallest denormal): sigma<=35 -> d>=7279; sigma<=15 -> d>=3120; sigma<=1 -> 208.
__device__ __forceinline__ float tail_sum(float d, const Coef& co) {
    float s = EXP2(d * co.c[10]) + EXP2(d * co.c[11])
            + EXP2(d * co.c[12]) + EXP2(d * co.c[13]);   // 20,25,30,35
    if (d < 3120.0f)
        s += EXP2(d * co.c[7]) + EXP2(d * co.c[8]) + EXP2(d * co.c[9]); // 5,10,15
    if (d < 208.0f)
        s += EXP2(d * co.c[0]) + EXP2(d * co.c[1]) + EXP2(d * co.c[2])
           + EXP2(d * co.c[3]) + EXP2(d * co.c[4]) + EXP2(d * co.c[5])
           + EXP2(d * co.c[6]);                           // sigma <= 1
    return s;
}

// --- kernel 3: the 6 multi-bandwidth Gaussian-kernel sums -------------------
// jobs: 0 wc_ss, 1 wc_tt, 2 wc_st, 3 bc_ss, 4 bc_tt, 5 bc_st
// Self jobs: strict upper triangle only (x2 + diag in finalize); block b does
// rows b and N-1-b for balance. Hot pairs (d<7280, ~2%/lane) are compacted
// into a per-wave LDS queue (ballot+mbcnt prefix) and drained 64-wide, so the
// rare-tier exps run dense instead of 1-2 live lanes per wave.
__global__ __launch_bounds__(256) void gk_all(float* __restrict__ ws, Coef co) {
    const float4* wcs = (const float4*)(ws + WS_WCS);
    const float4* wct = (const float4*)(ws + WS_WCT);
    const float4* bcs = (const float4*)(ws + WS_BCS);
    const float4* bct = (const float4*)(ws + WS_BCT);
    double* accs = (double*)((char*)ws + WS_ACC_BYTES);

    int b = blockIdx.x;
    int job, i;
    const float4 *X, *Y;
    int N; bool sym;
    if (b < GK_B2) {
        N = NWC;
        if (b < GK_B0)      { job = 0; i = b;          X = wcs; Y = wcs; sym = true;  }
        else if (b < GK_B1) { job = 1; i = b - GK_B0;  X = wct; Y = wct; sym = true;  }
        else                { job = 2; i = b - GK_B1;  X = wcs; Y = wct; sym = false; }
    } else {
        N = NBC;
        if (b < GK_B3)      { job = 3; i = b - GK_B2;  X = bcs; Y = bcs; sym = true;  }
        else if (b < GK_B4) { job = 4; i = b - GK_B3;  X = bct; Y = bct; sym = true;  }
        else                { job = 5; i = b - GK_B4;  X = bcs; Y = bct; sym = false; }
    }

    __shared__ float qbuf[4][128];
    __shared__ double wsum[4];
    int lane = threadIdx.x & 63, w = threadIdx.x >> 6;
    int qn = 0;            // wave-uniform queue depth (uniform trip count)
    double acc = 0.0;

    auto process = [&](float4 x, int jbeg) {
        int trips = (N - jbeg + 255) >> 8;   // uniform: padded Y covers overrun
        const float4* Yp = Y + jbeg + threadIdx.x;
        float accf = 0.f;
        for (int t = 0; t < trips; ++t) {
            float4 y = Yp[(size_t)t * 256];
            float d0 = x.x - y.x, d1 = x.y - y.y, d2 = x.z - y.z, d3 = x.w - y.w;
            float d = d0 * d0;
            d = fmaf(d1, d1, d);
            d = fmaf(d2, d2, d);
            d = fmaf(d3, d3, d);
            // mandatory sigmas: 100, 1e3, 1e4, 1e5, 1e6
            accf += EXP2(d * co.c[14]) + EXP2(d * co.c[15]) + EXP2(d * co.c[16])
                  + EXP2(d * co.c[17]) + EXP2(d * co.c[18]);
            bool hot = d < 7280.0f;
            unsigned long long m = __ballot(hot);
            int pre = __builtin_amdgcn_mbcnt_hi((unsigned)(m >> 32),
                       __builtin_amdgcn_mbcnt_lo((unsigned)m, 0u));
            if (hot) qbuf[w][qn + pre] = d;
            qn += (int)__popcll(m);
            if (qn >= 64) {          // dense drain: one full wave of tail work
                qn -= 64;
                float dq = qbuf[w][qn + lane];
                accf += tail_sum(dq, co);
            }
        }
        acc += (double)accf;
    };

    if (sym) {
        process(X[i], i + 1);
        int i1 = N - 1 - i;
        process(X[i1], i1 + 1);
    } else {
        process(X[i], 0);
    }

    // flush remaining queue entries (< 64)
    if (qn > 0) {
        float accf = 0.f;
        if (lane < qn) accf = tail_sum(qbuf[w][lane], co);
        acc += (double)accf;
    }

    // wave reduce (64 lanes), then block reduce 4 waves
    #pragma unroll
    for (int off = 32; off; off >>= 1) acc += __shfl_down(acc, off, 64);
    if (lane == 0) wsum[w] = acc;
    __syncthreads();
    if (threadIdx.x == 0) {
        double tot = wsum[0] + wsum[1] + wsum[2] + wsum[3];
        atomicAdd(&accs[job * NSLOT + (blockIdx.x & (NSLOT - 1))], tot);
    }
}

// --- kernel 4: combine into the two output scalars --------------------------
__global__ void finalize(const float* __restrict__ ws, float* __restrict__ out) {
    const double* accs = (const double*)((const char*)ws + WS_ACC_BYTES);
    int lane = threadIdx.x;  // blockDim = 64
    double p[6];
    #pragma unroll
    for (int q = 0; q < 6; ++q) {
        p[q] = accs[q * NSLOT + lane];
        #pragma unroll
        for (int off = 32; off; off >>= 1) p[q] += __shfl_down(p[q], off, 64);
    }
    if (lane == 0) {
        double t0 = 2.0 * p[0] + 19.0 * NWC;   // self: 2*triangle + diag(19 each)
        double t1 = 2.0 * p[1] + 19.0 * NWC;
        double t3 = 2.0 * p[3] + 19.0 * NBC;
        double t4 = 2.0 * p[4] + 19.0 * NBC;
        double nw = (double)NWC * (double)NWC;
        double nb = (double)NBC * (double)NBC;
        out[0] = (float)((t0 + t1 - 2.0 * p[2]) / nw);
        out[1] = (float)((t3 + t4 - 2.0 * p[5]) / nb);
    }
}

extern "C" void kernel_launch(void* const* d_in, const int* in_sizes, int n_in,
                              void* d_out, int out_size, void* d_ws, size_t ws_size,
                              hipStream_t stream) {
    const float* src = (const float*)d_in[0];
    const float* tgt = (const float*)d_in[1];
    float* out = (float*)d_out;
    float* ws = (float*)d_ws;

    static const double SIG[19] = {1e-06, 1e-05, 1e-04, 1e-03, 1e-02, 1e-01,
                                   1.0, 5.0, 10.0, 15.0, 20.0, 25.0, 30.0,
                                   35.0, 100.0, 1e3, 1e4, 1e5, 1e6};
    Coef co;
    for (int k = 0; k < 19; ++k)
        co.c[k] = (float)(-1.0 / (2.0 * SIG[k] * 0.6931471805599453));  // -log2e/(2s)

    compute_E<<<200, 256, 0, stream>>>(src, tgt, ws);
    scatter<<<27, 256, 0, stream>>>(ws);
    gk_all<<<GK_B5, 256, 0, stream>>>(ws, co);
    finalize<<<1, 64, 0, stream>>>(ws, out);
}

// Round 5
// 84.923 us; speedup vs baseline: 3.8480x; 1.0652x over previous
//
#include <hip/hip_runtime.h>

// ---------------------------------------------------------------------------
// MaximumMeanDiscrepancy: BATCH=160, INSTANCES=4, FEAT=1024, P=40
// out[0] = mmd(wcs, wct), out[1] = mmd(bcs, bct)
// ---------------------------------------------------------------------------

#define FEAT   1024
#define NROW   160     // BATCH
#define NPAIR  1522    // 1 + 39*39
#define NBC    6088    // NPAIR*4
#define NWC    160

// workspace layout (float offsets). bc/wc arrays are padded with 256 rows of
// 1e19f so the j-loop can run a uniform trip count: padded rows give d = inf
// -> every term is an exact 0.0f and the pair is never "hot".
#define WS_ES   0          // E_s [160*160]
#define WS_ET   25600      // E_t [160*160]
#define WS_BCS  51200      // bc_s [(6088+256)*4]
#define WS_BCT  76576      // bc_t
#define WS_WCS  101952     // wc_s [(160+256)*4]
#define WS_WCT  103616     // wc_t
#define WS_ACC_BYTES 421120  // 6*64 doubles
#define NSLOT  64

// flattened gk grid ranges: job lims {80,80,160,3044,3044,6088}
#define GK_B0   80
#define GK_B1   160
#define GK_B2   320
#define GK_B3   3364
#define GK_B4   6408
#define GK_B5   12496

struct Coef { float c[19]; };  // c[k] = -log2(e)/(2*sigma_k)  (exp2 form)

#if defined(__has_builtin)
#if __has_builtin(__builtin_amdgcn_exp2f)
#define EXP2(x) __builtin_amdgcn_exp2f(x)
#else
#define EXP2(x) exp2f(x)
#endif
#else
#define EXP2(x) exp2f(x)
#endif

// --- kernel 1: E[a,b] = ||f_a - f_b||^2 for both sides, 16x16 tiles ---------
__global__ __launch_bounds__(256) void compute_E(const float* __restrict__ Fs,
                                                 const float* __restrict__ Ft,
                                                 float* __restrict__ ws) {
    int side = blockIdx.x / 100;          // 0 = source, 1 = target
    int tile = blockIdx.x % 100;
    int trow = tile / 10, tcol = tile % 10;
    const float* F = side ? Ft : Fs;
    float* E = ws + (side ? WS_ET : WS_ES);

    __shared__ float As[16][132];
    __shared__ float Bs[16][132];
    int tid = threadIdx.x;
    int ti = tid >> 4, tj = tid & 15;
    int lr = tid >> 5;        // 0..7
    int lc4 = tid & 31;       // float4 column (0..31) of 128-dim chunk

    float acc = 0.f;
    for (int ch = 0; ch < 8; ++ch) {
        for (int rr = lr; rr < 16; rr += 8) {
            float4 a = *(const float4*)(F + (trow*16+rr)*FEAT + ch*128 + lc4*4);
            *(float4*)(&As[rr][lc4*4]) = a;
            float4 b = *(const float4*)(F + (tcol*16+rr)*FEAT + ch*128 + lc4*4);
            *(float4*)(&Bs[rr][lc4*4]) = b;
        }
        __syncthreads();
        #pragma unroll
        for (int c = 0; c < 128; c += 4) {
            float4 a = *(const float4*)(&As[ti][c]);
            float4 b = *(const float4*)(&Bs[tj][c]);
            float d0 = a.x - b.x, d1 = a.y - b.y, d2 = a.z - b.z, d3 = a.w - b.w;
            acc = fmaf(d0, d0, acc);
            acc = fmaf(d1, d1, acc);
            acc = fmaf(d2, d2, acc);
            acc = fmaf(d3, d3, acc);
        }
        __syncthreads();
    }
    E[(trow*16+ti)*NROW + tcol*16 + tj] = acc;
}

// --- kernel 2: gather wc/bc rows from E; pad rows; zero accumulators --------
__global__ __launch_bounds__(256) void scatter(float* __restrict__ ws) {
    int idx = blockIdx.x * blockDim.x + threadIdx.x;
    const float* E_s = ws + WS_ES;
    const float* E_t = ws + WS_ET;
    float4* bc_s = (float4*)(ws + WS_BCS);
    float4* bc_t = (float4*)(ws + WS_BCT);
    float4* wc_s = (float4*)(ws + WS_WCS);
    float4* wc_t = (float4*)(ws + WS_WCT);
    double* accs = (double*)((char*)ws + WS_ACC_BYTES);

    if (idx < 6 * NSLOT) accs[idx] = 0.0;

    if (idx < NBC) {
        int t = idx >> 2, ii = idx & 3;
        int pi, pj;
        if (t == 0) { pi = 0; pj = 1; }
        else {
            int tt = t - 1;
            pi = 1 + tt / 39;
            int jj = tt % 39;
            pj = (jj < pi) ? jj : jj + 1;
        }
        bc_s[idx] = *(const float4*)(E_s + (4*pi + ii)*NROW + 4*pj);
        bc_t[idx] = *(const float4*)(E_t + (4*pi + ii)*NROW + 4*pj);
    } else if (idx < NBC + NWC) {
        int r = idx - NBC;
        int p = r >> 2;
        wc_s[r] = *(const float4*)(E_s + r*NROW + 4*p);
        wc_t[r] = *(const float4*)(E_t + r*NROW + 4*p);
    } else if (idx < NBC + NWC + 256) {
        int p = idx - (NBC + NWC);
        float4 pad = make_float4(1e19f, 1e19f, 1e19f, 1e19f);
        bc_s[NBC + p] = pad;
        bc_t[NBC + p] = pad;
    } else if (idx < NBC + NWC + 512) {
        int p = idx - (NBC + NWC + 256);
        float4 pad = make_float4(1e19f, 1e19f, 1e19f, 1e19f);
        wc_s[NWC + p] = pad;
        wc_t[NWC + p] = pad;
    }
}

// --- tail terms for hot pairs (d < 7280): sigma <= 35 tiers -----------------
// Tier-skip is exact: exp2(d*c) == 0.0f once d*c <= -150:
// sigma<=35 -> d>=7279; sigma<=15 -> d>=3120; sigma<=1 -> 208.
__device__ __forceinline__ float tail_sum(float d, const Coef& co) {
    float s = EXP2(d * co.c[10]) + EXP2(d * co.c[11])
            + EXP2(d * co.c[12]) + EXP2(d * co.c[13]);   // 20,25,30,35
    if (d < 3120.0f)
        s += EXP2(d * co.c[7]) + EXP2(d * co.c[8]) + EXP2(d * co.c[9]); // 5,10,15
    if (d < 208.0f)
        s += EXP2(d * co.c[0]) + EXP2(d * co.c[1]) + EXP2(d * co.c[2])
           + EXP2(d * co.c[3]) + EXP2(d * co.c[4]) + EXP2(d * co.c[5])
           + EXP2(d * co.c[6]);                           // sigma <= 1
    return s;
}

// pow10 chain: x^10 = ((x^4)*x)^2 computed as x2=x*x, x4=x2*x2, x5=x4*x, x10=x5*x5
__device__ __forceinline__ float pow10f(float x) {
    float x2 = x * x;
    float x4 = x2 * x2;
    float x5 = x4 * x;
    return x5 * x5;
}

// --- kernel 3: the 6 multi-bandwidth Gaussian-kernel sums -------------------
// jobs: 0 wc_ss, 1 wc_tt, 2 wc_st, 3 bc_ss, 4 bc_tt, 5 bc_st
// Self jobs: strict upper triangle only (x2 + diag in finalize); block b does
// rows b and N-1-b for balance. Hot pairs (d<7280, ~2%/lane) are compacted
// into a per-wave LDS queue (ballot+mbcnt prefix) and drained 64-wide.
// Upper sigmas use exp power-chains: exp2(10*x) = exp2(x)^10, so only 2 hw
// exps (sigma=1e6, 1e4); sigma=1e5 = e6^10, 1e3 = e4^10, 100 = (e4^10)^10.
// Chain rel-err <= ~1e-5, cancels in the mmd difference; underflow chains to
// exact 0 and d=0 gives exactly 1, consistent with the hw-exp path.
__global__ __launch_bounds__(256) void gk_all(float* __restrict__ ws, Coef co) {
    const float4* wcs = (const float4*)(ws + WS_WCS);
    const float4* wct = (const float4*)(ws + WS_WCT);
    const float4* bcs = (const float4*)(ws + WS_BCS);
    const float4* bct = (const float4*)(ws + WS_BCT);
    double* accs = (double*)((char*)ws + WS_ACC_BYTES);

    int b = blockIdx.x;
    int job, i;
    const float4 *X, *Y;
    int N; bool sym;
    if (b < GK_B2) {
        N = NWC;
        if (b < GK_B0)      { job = 0; i = b;          X = wcs; Y = wcs; sym = true;  }
        else if (b < GK_B1) { job = 1; i = b - GK_B0;  X = wct; Y = wct; sym = true;  }
        else                { job = 2; i = b - GK_B1;  X = wcs; Y = wct; sym = false; }
    } else {
        N = NBC;
        if (b < GK_B3)      { job = 3; i = b - GK_B2;  X = bcs; Y = bcs; sym = true;  }
        else if (b < GK_B4) { job = 4; i = b - GK_B3;  X = bct; Y = bct; sym = true;  }
        else                { job = 5; i = b - GK_B4;  X = bcs; Y = bct; sym = false; }
    }

    __shared__ float qbuf[4][128];
    __shared__ double wsum[4];
    int lane = threadIdx.x & 63, w = threadIdx.x >> 6;
    int qn = 0;            // wave-uniform queue depth
    double acc = 0.0;

    auto process = [&](float4 x, int jbeg) {
        int trips = (N - jbeg + 255) >> 8;   // uniform: padded Y covers overrun
        const float4* Yp = Y + jbeg + threadIdx.x;
        float accf = 0.f;
        for (int t = 0; t < trips; ++t) {
            float4 y = Yp[(size_t)t * 256];
            float d0 = x.x - y.x, d1 = x.y - y.y, d2 = x.z - y.z, d3 = x.w - y.w;
            float d = d0 * d0;
            d = fmaf(d1, d1, d);
            d = fmaf(d2, d2, d);
            d = fmaf(d3, d3, d);
            // sigma = 1e6, 1e4 via hw exp; 1e5, 1e3, 100 via ^10 chains
            float e6  = EXP2(d * co.c[18]);
            float e4  = EXP2(d * co.c[16]);
            float e5  = pow10f(e6);
            float e3  = pow10f(e4);
            float e100 = pow10f(e3);
            accf += ((e6 + e5) + (e4 + e3)) + e100;
            bool hot = d < 7280.0f;
            unsigned long long m = __ballot(hot);
            int pre = __builtin_amdgcn_mbcnt_hi((unsigned)(m >> 32),
                       __builtin_amdgcn_mbcnt_lo((unsigned)m, 0u));
            if (hot) qbuf[w][qn + pre] = d;
            qn += (int)__popcll(m);
            if (qn >= 64) {          // dense drain: one full wave of tail work
                qn -= 64;
                float dq = qbuf[w][qn + lane];
                accf += tail_sum(dq, co);
            }
        }
        acc += (double)accf;
    };

    if (sym) {
        process(X[i], i + 1);
        int i1 = N - 1 - i;
        process(X[i1], i1 + 1);
    } else {
        process(X[i], 0);
    }

    // flush remaining queue entries (< 64)
    if (qn > 0) {
        float accf = 0.f;
        if (lane < qn) accf = tail_sum(qbuf[w][lane], co);
        acc += (double)accf;
    }

    // wave reduce (64 lanes), then block reduce 4 waves
    #pragma unroll
    for (int off = 32; off; off >>= 1) acc += __shfl_down(acc, off, 64);
    if (lane == 0) wsum[w] = acc;
    __syncthreads();
    if (threadIdx.x == 0) {
        double tot = wsum[0] + wsum[1] + wsum[2] + wsum[3];
        atomicAdd(&accs[job * NSLOT + (blockIdx.x & (NSLOT - 1))], tot);
    }
}

// --- kernel 4: combine into the two output scalars --------------------------
__global__ void finalize(const float* __restrict__ ws, float* __restrict__ out) {
    const double* accs = (const double*)((const char*)ws + WS_ACC_BYTES);
    int lane = threadIdx.x;  // blockDim = 64
    double p[6];
    #pragma unroll
    for (int q = 0; q < 6; ++q) {
        p[q] = accs[q * NSLOT + lane];
        #pragma unroll
        for (int off = 32; off; off >>= 1) p[q] += __shfl_down(p[q], off, 64);
    }
    if (lane == 0) {
        double t0 = 2.0 * p[0] + 19.0 * NWC;   // self: 2*triangle + diag(19 each)
        double t1 = 2.0 * p[1] + 19.0 * NWC;
        double t3 = 2.0 * p[3] + 19.0 * NBC;
        double t4 = 2.0 * p[4] + 19.0 * NBC;
        double nw = (double)NWC * (double)NWC;
        double nb = (double)NBC * (double)NBC;
        out[0] = (float)((t0 + t1 - 2.0 * p[2]) / nw);
        out[1] = (float)((t3 + t4 - 2.0 * p[5]) / nb);
    }
}

extern "C" void kernel_launch(void* const* d_in, const int* in_sizes, int n_in,
                              void* d_out, int out_size, void* d_ws, size_t ws_size,
                              hipStream_t stream) {
    const float* src = (const float*)d_in[0];
    const float* tgt = (const float*)d_in[1];
    float* out = (float*)d_out;
    float* ws = (float*)d_ws;

    static const double SIG[19] = {1e-06, 1e-05, 1e-04, 1e-03, 1e-02, 1e-01,
                                   1.0, 5.0, 10.0, 15.0, 20.0, 25.0, 30.0,
                                   35.0, 100.0, 1e3, 1e4, 1e5, 1e6};
    Coef co;
    for (int k = 0; k < 19; ++k)
        co.c[k] = (float)(-1.0 / (2.0 * SIG[k] * 0.6931471805599453));  // -log2e/(2s)

    compute_E<<<200, 256, 0, stream>>>(src, tgt, ws);
    scatter<<<27, 256, 0, stream>>>(ws);
    gk_all<<<GK_B5, 256, 0, stream>>>(ws, co);
    finalize<<<1, 64, 0, stream>>>(ws, out);
}

// Round 6
// 83.506 us; speedup vs baseline: 3.9133x; 1.0170x over previous
//
#include <hip/hip_runtime.h>

// ---------------------------------------------------------------------------
// MaximumMeanDiscrepancy: BATCH=160, INSTANCES=4, FEAT=1024, P=40
// out[0] = mmd(wcs, wct), out[1] = mmd(bcs, bct)
// ---------------------------------------------------------------------------

#define FEAT   1024
#define NROW   160     // BATCH
#define NBC    6088    // (1 + 39*39) * 4
#define NWC    160
#define NBCBLK 3044    // NBC/2 fused-triangle blocks
#define GKBLK  3124    // + NWC/2

// workspace layout (float offsets). bci/wci are INTERLEAVED: row i is
// {source float4, target float4}. 256 pad rows of 1e19f follow each array so
// the j-loop runs a uniform trip count (pad d -> huge -> all terms exact 0,
// never hot).
#define WS_ES   0          // E_s [160*160]
#define WS_ET   25600      // E_t [160*160]
#define WS_BCI  51200      // bci [(6088+256)*8]
#define WS_WCI  101952     // wci [(160+256)*8]
#define WS_ACC_BYTES 421120  // 6*64 doubles
#define NSLOT  64

struct Coef { float c[19]; };  // c[k] = -log2(e)/(2*sigma_k)  (exp2 form)

#if defined(__has_builtin)
#if __has_builtin(__builtin_amdgcn_exp2f)
#define EXP2(x) __builtin_amdgcn_exp2f(x)
#else
#define EXP2(x) exp2f(x)
#endif
#else
#define EXP2(x) exp2f(x)
#endif

// --- kernel 1: E[a,b] = ||f_a - f_b||^2 for both sides, 16x16 tiles ---------
__global__ __launch_bounds__(256) void compute_E(const float* __restrict__ Fs,
                                                 const float* __restrict__ Ft,
                                                 float* __restrict__ ws) {
    int side = blockIdx.x / 100;          // 0 = source, 1 = target
    int tile = blockIdx.x % 100;
    int trow = tile / 10, tcol = tile % 10;
    const float* F = side ? Ft : Fs;
    float* E = ws + (side ? WS_ET : WS_ES);

    __shared__ float As[16][132];
    __shared__ float Bs[16][132];
    int tid = threadIdx.x;
    int ti = tid >> 4, tj = tid & 15;
    int lr = tid >> 5;        // 0..7
    int lc4 = tid & 31;       // float4 column (0..31) of 128-dim chunk

    float acc = 0.f;
    for (int ch = 0; ch < 8; ++ch) {
        for (int rr = lr; rr < 16; rr += 8) {
            float4 a = *(const float4*)(F + (trow*16+rr)*FEAT + ch*128 + lc4*4);
            *(float4*)(&As[rr][lc4*4]) = a;
            float4 b = *(const float4*)(F + (tcol*16+rr)*FEAT + ch*128 + lc4*4);
            *(float4*)(&Bs[rr][lc4*4]) = b;
        }
        __syncthreads();
        #pragma unroll
        for (int c = 0; c < 128; c += 4) {
            float4 a = *(const float4*)(&As[ti][c]);
            float4 b = *(const float4*)(&Bs[tj][c]);
            float d0 = a.x - b.x, d1 = a.y - b.y, d2 = a.z - b.z, d3 = a.w - b.w;
            acc = fmaf(d0, d0, acc);
            acc = fmaf(d1, d1, acc);
            acc = fmaf(d2, d2, acc);
            acc = fmaf(d3, d3, acc);
        }
        __syncthreads();
    }
    E[(trow*16+ti)*NROW + tcol*16 + tj] = acc;
}

// --- kernel 2: gather interleaved bci/wci rows; pad; zero accumulators ------
__global__ __launch_bounds__(256) void scatter(float* __restrict__ ws) {
    int idx = blockIdx.x * blockDim.x + threadIdx.x;
    const float* E_s = ws + WS_ES;
    const float* E_t = ws + WS_ET;
    float4* bci = (float4*)(ws + WS_BCI);
    float4* wci = (float4*)(ws + WS_WCI);
    double* accs = (double*)((char*)ws + WS_ACC_BYTES);

    if (idx < 6 * NSLOT) accs[idx] = 0.0;

    if (idx < NBC) {
        int t = idx >> 2, ii = idx & 3;
        int pi, pj;
        if (t == 0) { pi = 0; pj = 1; }
        else {
            int tt = t - 1;
            pi = 1 + tt / 39;
            int jj = tt % 39;
            pj = (jj < pi) ? jj : jj + 1;
        }
        bci[2*idx]   = *(const float4*)(E_s + (4*pi + ii)*NROW + 4*pj);
        bci[2*idx+1] = *(const float4*)(E_t + (4*pi + ii)*NROW + 4*pj);
    } else if (idx < NBC + NWC) {
        int r = idx - NBC;
        int p = r >> 2;
        wci[2*r]   = *(const float4*)(E_s + r*NROW + 4*p);
        wci[2*r+1] = *(const float4*)(E_t + r*NROW + 4*p);
    } else if (idx < NBC + NWC + 256) {
        int p = NBC + (idx - (NBC + NWC));
        float4 pad = make_float4(1e19f, 1e19f, 1e19f, 1e19f);
        bci[2*p] = pad;
        bci[2*p+1] = pad;
    } else if (idx < NBC + NWC + 512) {
        int p = NWC + (idx - (NBC + NWC + 256));
        float4 pad = make_float4(1e19f, 1e19f, 1e19f, 1e19f);
        wci[2*p] = pad;
        wci[2*p+1] = pad;
    }
}

// --- tail terms for hot pairs (d < 7280): sigma <= 35 tiers -----------------
// Tier-skip is exact: exp2(d*c) == 0.0f once d*c <= -150:
// sigma<=35 -> d>=7279; sigma<=15 -> d>=3120; sigma<=1 -> 208.
__device__ __forceinline__ float tail_sum(float d, const Coef& co) {
    float s = EXP2(d * co.c[10]) + EXP2(d * co.c[11])
            + EXP2(d * co.c[12]) + EXP2(d * co.c[13]);   // 20,25,30,35
    if (d < 3120.0f)
        s += EXP2(d * co.c[7]) + EXP2(d * co.c[8]) + EXP2(d * co.c[9]); // 5,10,15
    if (d < 208.0f)
        s += EXP2(d * co.c[0]) + EXP2(d * co.c[1]) + EXP2(d * co.c[2])
           + EXP2(d * co.c[3]) + EXP2(d * co.c[4]) + EXP2(d * co.c[5])
           + EXP2(d * co.c[6]);                           // sigma <= 1
    return s;
}

// x^10 = x2=x*x, x4=x2*x2, x5=x4*x, x10=x5*x5
__device__ __forceinline__ float pow10f(float x) {
    float x2 = x * x;
    float x4 = x2 * x2;
    float x5 = x4 * x;
    return x5 * x5;
}

// mandatory sigmas {100,1e3,1e4,1e5,1e6}: 2 hw exps + ^10 chains
// (1e5 = e6^10, 1e3 = e4^10, 100 = e3^10); chain rel-err <= ~1e-5.
__device__ __forceinline__ float mand(float d, const Coef& co) {
    float e6 = EXP2(d * co.c[18]);
    float e4 = EXP2(d * co.c[16]);
    float e5 = pow10f(e6);
    float e3 = pow10f(e4);
    float e100 = pow10f(e3);
    return ((e6 + e5) + (e4 + e3)) + e100;
}

__device__ __forceinline__ float sqd(float4 a, float4 b) {
    float d0 = a.x - b.x, d1 = a.y - b.y, d2 = a.z - b.z, d3 = a.w - b.w;
    float d = d0 * d0;
    d = fmaf(d1, d1, d);
    d = fmaf(d2, d2, d);
    return fmaf(d3, d3, d);
}

// --- kernel 3: fused triangle sweep -----------------------------------------
// Block b < NBCBLK: bc rows i=b and 6087-b; else wc rows i and 159-i.
// Per (i,j>i): 4 evals sharing the y load: (s_i,s_j)->ss, (t_i,t_j)->tt,
// (s_i,t_j)+(t_i,s_j)->st. Full st matrix = triangle both-dirs + diag
// (diag in gk_diag). Hot pairs (d<7280) compacted into 3 per-wave LDS
// queues (ballot+mbcnt), drained 64-wide dense.
__global__ __launch_bounds__(256) void gk_fused(float* __restrict__ ws, Coef co) {
    double* accs = (double*)((char*)ws + WS_ACC_BYTES);
    int b = blockIdx.x;
    const float4* Yv; int N, jb, i0;
    if (b < NBCBLK) { Yv = (const float4*)(ws + WS_BCI); N = NBC; jb = 3; i0 = b; }
    else            { Yv = (const float4*)(ws + WS_WCI); N = NWC; jb = 0; i0 = b - NBCBLK; }

    __shared__ float qb[4][3][192];
    __shared__ double wsum[4][3];
    int lane = threadIdx.x & 63, w = threadIdx.x >> 6;
    int qn0 = 0, qn1 = 0, qn2 = 0;   // wave-uniform queue depths
    double a0 = 0.0, a1 = 0.0, a2 = 0.0;

#define MBCNT(m) __builtin_amdgcn_mbcnt_hi((unsigned)((m) >> 32), \
                  __builtin_amdgcn_mbcnt_lo((unsigned)(m), 0u))
#define PUSHQ(Q, QN, dv) { bool hot_ = (dv) < 7280.0f;              \
        unsigned long long m_ = __ballot(hot_);                      \
        if (hot_) qb[w][Q][QN + MBCNT(m_)] = (dv);                   \
        QN += (int)__popcll(m_); }
#define DRAINQ(Q, QN, ACC) if (QN >= 64) { QN -= 64;                 \
        float dq_ = qb[w][Q][QN + lane];                             \
        ACC += (double)tail_sum(dq_, co); }

    auto process = [&](int i) {
        float4 xs = Yv[2*i], xt = Yv[2*i+1];
        int jbeg = i + 1;
        int trips = (N - jbeg + 255) >> 8;
        const float4* Yp = Yv + 2*(jbeg + (int)threadIdx.x);
        float m0 = 0.f, m1 = 0.f, m2 = 0.f;
        for (int t = 0; t < trips; ++t) {
            float4 ys = Yp[0], yt = Yp[1];
            Yp += 512;
            float dss = sqd(xs, ys);
            float dtt = sqd(xt, yt);
            float dst = sqd(xs, yt);
            float dts = sqd(xt, ys);
            m0 += mand(dss, co);
            m1 += mand(dtt, co);
            m2 += mand(dst, co) + mand(dts, co);
            PUSHQ(0, qn0, dss); DRAINQ(0, qn0, a0);
            PUSHQ(1, qn1, dtt); DRAINQ(1, qn1, a1);
            PUSHQ(2, qn2, dst);
            PUSHQ(2, qn2, dts); DRAINQ(2, qn2, a2); DRAINQ(2, qn2, a2);
        }
        a0 += (double)m0; a1 += (double)m1; a2 += (double)m2;
    };

    process(i0);
    process(N - 1 - i0);

    // flush remaining queue entries (< 64 each)
    if (lane < qn0) a0 += (double)tail_sum(qb[w][0][lane], co);
    if (lane < qn1) a1 += (double)tail_sum(qb[w][1][lane], co);
    if (lane < qn2) a2 += (double)tail_sum(qb[w][2][lane], co);

    // wave reduce, then block reduce 4 waves, 3 jobs
    #pragma unroll
    for (int off = 32; off; off >>= 1) {
        a0 += __shfl_down(a0, off, 64);
        a1 += __shfl_down(a1, off, 64);
        a2 += __shfl_down(a2, off, 64);
    }
    if (lane == 0) { wsum[w][0] = a0; wsum[w][1] = a1; wsum[w][2] = a2; }
    __syncthreads();
    if (threadIdx.x < 3) {
        int q = threadIdx.x;
        double tot = wsum[0][q] + wsum[1][q] + wsum[2][q] + wsum[3][q];
        atomicAdd(&accs[(jb + q) * NSLOT + (b & (NSLOT - 1))], tot);
    }
#undef PUSHQ
#undef DRAINQ
#undef MBCNT
}

// --- kernel 3b: st diagonal terms k(s_i, t_i) -------------------------------
__global__ __launch_bounds__(256) void gk_diag(float* __restrict__ ws, Coef co) {
    double* accs = (double*)((char*)ws + WS_ACC_BYTES);
    int idx = blockIdx.x * 256 + threadIdx.x;
    double v5 = 0.0, v2 = 0.0;
    if (idx < NBC) {
        const float4* bci = (const float4*)(ws + WS_BCI);
        float d = sqd(bci[2*idx], bci[2*idx+1]);
        float s = mand(d, co);
        if (d < 7280.0f) s += tail_sum(d, co);
        v5 = (double)s;
    } else if (idx < NBC + NWC) {
        int r = idx - NBC;
        const float4* wci = (const float4*)(ws + WS_WCI);
        float d = sqd(wci[2*r], wci[2*r+1]);
        float s = mand(d, co);
        if (d < 7280.0f) s += tail_sum(d, co);
        v2 = (double)s;
    }
    #pragma unroll
    for (int off = 32; off; off >>= 1) {
        v5 += __shfl_down(v5, off, 64);
        v2 += __shfl_down(v2, off, 64);
    }
    __shared__ double s5[4], s2[4];
    int lane = threadIdx.x & 63, w = threadIdx.x >> 6;
    if (lane == 0) { s5[w] = v5; s2[w] = v2; }
    __syncthreads();
    if (threadIdx.x == 0) {
        atomicAdd(&accs[5 * NSLOT + (blockIdx.x & (NSLOT - 1))],
                  s5[0] + s5[1] + s5[2] + s5[3]);
        atomicAdd(&accs[2 * NSLOT + (blockIdx.x & (NSLOT - 1))],
                  s2[0] + s2[1] + s2[2] + s2[3]);
    }
}

// --- kernel 4: combine into the two output scalars --------------------------
__global__ void finalize(const float* __restrict__ ws, float* __restrict__ out) {
    const double* accs = (const double*)((const char*)ws + WS_ACC_BYTES);
    int lane = threadIdx.x;  // blockDim = 64
    double p[6];
    #pragma unroll
    for (int q = 0; q < 6; ++q) {
        p[q] = accs[q * NSLOT + lane];
        #pragma unroll
        for (int off = 32; off; off >>= 1) p[q] += __shfl_down(p[q], off, 64);
    }
    if (lane == 0) {
        double t0 = 2.0 * p[0] + 19.0 * NWC;   // self: 2*triangle + diag
        double t1 = 2.0 * p[1] + 19.0 * NWC;
        double t3 = 2.0 * p[3] + 19.0 * NBC;
        double t4 = 2.0 * p[4] + 19.0 * NBC;
        double nw = (double)NWC * (double)NWC;
        double nb = (double)NBC * (double)NBC;
        out[0] = (float)((t0 + t1 - 2.0 * p[2]) / nw);   // p2 = tri both dirs + diag
        out[1] = (float)((t3 + t4 - 2.0 * p[5]) / nb);
    }
}

extern "C" void kernel_launch(void* const* d_in, const int* in_sizes, int n_in,
                              void* d_out, int out_size, void* d_ws, size_t ws_size,
                              hipStream_t stream) {
    const float* src = (const float*)d_in[0];
    const float* tgt = (const float*)d_in[1];
    float* out = (float*)d_out;
    float* ws = (float*)d_ws;

    static const double SIG[19] = {1e-06, 1e-05, 1e-04, 1e-03, 1e-02, 1e-01,
                                   1.0, 5.0, 10.0, 15.0, 20.0, 25.0, 30.0,
                                   35.0, 100.0, 1e3, 1e4, 1e5, 1e6};
    Coef co;
    for (int k = 0; k < 19; ++k)
        co.c[k] = (float)(-1.0 / (2.0 * SIG[k] * 0.6931471805599453));  // -log2e/(2s)

    compute_E<<<200, 256, 0, stream>>>(src, tgt, ws);
    scatter<<<27, 256, 0, stream>>>(ws);
    gk_fused<<<GKBLK, 256, 0, stream>>>(ws, co);
    gk_diag<<<25, 256, 0, stream>>>(ws, co);
    finalize<<<1, 64, 0, stream>>>(ws, out);
}